// Round 1
// baseline (67.601 us; speedup 1.0000x reference)
//
#include <hip/hip_runtime.h>

// Problem constants (match reference.py)
constexpr int N = 4096;   // points
constexpr int M = 1024;   // queries
constexpr int C = 64;     // channels
constexpr int GRID = 20;             // 20x20 cells of size 0.05 over [0,1)^2
constexpr int NCELL = GRID * GRID;   // 400
#define CELL_INV 20.0f
#define HALF_KW 0.05f     // kernel_size/2, strict '<' per reference
#define NEG_INF (-3.402823466e38f)   // jnp.finfo(float32).min == -FLT_MAX

// Workspace layout (d_ws, all regions fully written before read each launch):
//   offset 0      : int   cell_start[NCELL+1]   (1604 B)
//   offset 4096   : int   binned_idx[N]         (16 KB)
//   offset 20480  : float2 binned_xy[N]         (32 KB)

// ---------------- Kernel 1: bin the 4096 points (single block) ----------------
// Count per-cell via LDS atomics, Hillis-Steele scan of 400 counters,
// scatter point index + coords into cell-sorted order. Cells are numbered
// cy*GRID+cx, so a run of cells within one cy-row is CONTIGUOUS in the
// binned arrays -> each query later reads <=3 contiguous segments.
__global__ __launch_bounds__(1024) void bin_points_kernel(
    const float* __restrict__ coords,      // [N, 2]
    int* __restrict__ cell_start,          // [NCELL+1]
    int* __restrict__ binned_idx,          // [N]
    float2* __restrict__ binned_xy)        // [N]
{
    __shared__ int s_cnt[NCELL];
    __shared__ int s_scan[512];
    __shared__ int s_cur[NCELL];

    const int tid = threadIdx.x;   // 0..1023, 4 points per thread

    if (tid < NCELL) s_cnt[tid] = 0;
    __syncthreads();

    // load 4 points (two float4 = 4 float2 coords), keep in registers
    const float4* c4 = (const float4*)coords;
    const float4 a = c4[2 * tid];
    const float4 b = c4[2 * tid + 1];
    const float px[4] = {a.x, a.z, b.x, b.z};
    const float py[4] = {a.y, a.w, b.y, b.w};
    int cell[4];
    #pragma unroll
    for (int k = 0; k < 4; ++k) {
        const int cx = min(GRID - 1, (int)(px[k] * CELL_INV));
        const int cy = min(GRID - 1, (int)(py[k] * CELL_INV));
        cell[k] = cy * GRID + cx;
        atomicAdd(&s_cnt[cell[k]], 1);
    }
    __syncthreads();

    // inclusive scan of 400 counters (padded to 512)
    if (tid < 512) s_scan[tid] = (tid < NCELL) ? s_cnt[tid] : 0;
    __syncthreads();
    for (int off = 1; off < 512; off <<= 1) {
        int v = 0;
        if (tid < 512) { v = s_scan[tid]; if (tid >= off) v += s_scan[tid - off]; }
        __syncthreads();
        if (tid < 512) s_scan[tid] = v;
        __syncthreads();
    }
    // exclusive starts; cell_start[NCELL] = N
    if (tid <= NCELL) {
        const int e = (tid == 0) ? 0 : s_scan[tid - 1];
        cell_start[tid] = e;
        if (tid < NCELL) s_cur[tid] = e;
    }
    __syncthreads();

    // scatter (order within a cell is arbitrary -> harmless under max)
    #pragma unroll
    for (int k = 0; k < 4; ++k) {
        const int pos = atomicAdd(&s_cur[cell[k]], 1);
        binned_idx[pos] = 4 * tid + k;
        binned_xy[pos]  = make_float2(px[k], py[k]);
    }
}

// ---------------- Kernel 2: one block (256 thr) per query ----------------
// Phase A: test only the <=3 contiguous binned segments covering the query
//          box (~94 candidates vs 4096), compact hits into LDS list.
//          Cell ranges widened by 1e-4 -> provable superset of the strict
//          f32 test, which itself is bit-identical to the reference.
// Phase B: grouped float4 gather (unchanged, verified): lane=(sub<<4)|cq,
//          each lane loads a float4 of values (16 B/lane), groups of 4
//          points round-robin over the 4 waves.
// Phase C: 16 partials per channel-quad reduced by threads 0..15.
__global__ __launch_bounds__(256) void maxpool_query_kernel(
    const float* __restrict__ values,      // [N, C]
    const float* __restrict__ qcoords,     // [M, 2]
    const int* __restrict__ cell_start,    // [NCELL+1]
    const int* __restrict__ binned_idx,    // [N]
    const float2* __restrict__ binned_xy,  // [N]
    float* __restrict__ out)               // [M, C]
{
    __shared__ int    s_cnt;
    __shared__ int    s_list[N];          // worst-case all points match
    __shared__ float4 s_part[16][16];     // [w*4+sub][cq]

    const int q    = blockIdx.x;
    const int tid  = threadIdx.x;         // 0..255
    const int lane = tid & 63;
    const int w    = tid >> 6;            // wave id 0..3

    if (tid == 0) s_cnt = 0;

    const float qx = qcoords[2 * q + 0];
    const float qy = qcoords[2 * q + 1];

    // candidate cell ranges (superset of any point passing the strict test)
    const int cx0 = max(0,        (int)floorf((qx - HALF_KW - 1e-4f) * CELL_INV));
    const int cx1 = min(GRID - 1, (int)floorf((qx + HALF_KW + 1e-4f) * CELL_INV));
    const int cy0 = max(0,        (int)floorf((qy - HALF_KW - 1e-4f) * CELL_INV));
    const int cy1 = min(GRID - 1, (int)floorf((qy + HALF_KW + 1e-4f) * CELL_INV));
    const int nrows = cy1 - cy0 + 1;      // 1..3 (box spans <=3 cells/dim)

    // up to 3 row-contiguous segments of binned points
    int base[3], len[3];
    #pragma unroll
    for (int r = 0; r < 3; ++r) {
        if (r < nrows) {
            const int row = (cy0 + r) * GRID;
            const int lo = cell_start[row + cx0];
            const int hi = cell_start[row + cx1 + 1];
            base[r] = lo; len[r] = hi - lo;
        } else { base[r] = 0; len[r] = 0; }
    }
    const int total = len[0] + len[1] + len[2];   // ~94 expected
    __syncthreads();   // s_cnt=0 visible before any atomicAdd

    // ---- Phase A: flattened candidate test + compaction (1 pass typical) ----
    for (int t = tid; t < total; t += 256) {
        int j;
        if (t < len[0])               j = base[0] + t;
        else if (t < len[0] + len[1]) j = base[1] + (t - len[0]);
        else                          j = base[2] + (t - len[0] - len[1]);
        const float2 cc = binned_xy[j];
        if (fabsf(qx - cc.x) < HALF_KW && fabsf(qy - cc.y) < HALF_KW) {
            const int k = atomicAdd(&s_cnt, 1);
            s_list[k] = binned_idx[j];
        }
    }
    __syncthreads();

    const int cnt = s_cnt;
    const int G   = (cnt + 3) >> 2;              // groups of 4 points
    if (cnt > 0 && tid < G * 4 - cnt) s_list[cnt + tid] = s_list[0];
    __syncthreads();

    // ---- Phase B: grouped float4 gather ----
    const int sub = lane >> 4;                   // point-in-group 0..3
    const int cq  = lane & 15;                   // channel quad 0..15
    const float4* v4 = (const float4*)values;    // [N][16] float4
    float4 acc = make_float4(NEG_INF, NEG_INF, NEG_INF, NEG_INF);
    for (int g = w; g < G; g += 4) {
        const int p = s_list[g * 4 + sub];       // LDS broadcast within 16 lanes
        const float4 v = v4[p * 16 + cq];        // coalesced 16 B/lane
        acc.x = fmaxf(acc.x, v.x);
        acc.y = fmaxf(acc.y, v.y);
        acc.z = fmaxf(acc.z, v.z);
        acc.w = fmaxf(acc.w, v.w);
    }
    s_part[w * 4 + sub][cq] = acc;
    __syncthreads();

    // ---- Phase C: reduce 16 partials per channel quad, write out ----
    if (tid < 16) {
        float4 r = s_part[0][tid];
        #pragma unroll
        for (int k = 1; k < 16; ++k) {
            const float4 t = s_part[k][tid];
            r.x = fmaxf(r.x, t.x);
            r.y = fmaxf(r.y, t.y);
            r.z = fmaxf(r.z, t.z);
            r.w = fmaxf(r.w, t.w);
        }
        ((float4*)out)[q * 16 + tid] = r;
    }
}

extern "C" void kernel_launch(void* const* d_in, const int* in_sizes, int n_in,
                              void* d_out, int out_size, void* d_ws, size_t ws_size,
                              hipStream_t stream) {
    const float* values  = (const float*)d_in[0];  // [4096, 64]
    const float* coords  = (const float*)d_in[1];  // [4096, 2]
    const float* qcoords = (const float*)d_in[2];  // [1024, 2]
    float* out = (float*)d_out;                    // [1024, 64]

    char* ws = (char*)d_ws;
    int*    cell_start = (int*)(ws + 0);
    int*    binned_idx = (int*)(ws + 4096);
    float2* binned_xy  = (float2*)(ws + 20480);

    bin_points_kernel<<<1, 1024, 0, stream>>>(coords, cell_start, binned_idx, binned_xy);
    maxpool_query_kernel<<<M, 256, 0, stream>>>(values, qcoords, cell_start,
                                                binned_idx, binned_xy, out);
}

// Round 2
// 62.997 us; speedup vs baseline: 1.0731x; 1.0731x over previous
//
#include <hip/hip_runtime.h>

// Problem constants (match reference.py)
constexpr int N = 4096;   // points
constexpr int M = 1024;   // queries
constexpr int C = 64;     // channels (== wave width!)
#define HALF_KW 0.05f     // kernel_size/2, strict '<' per reference
#define NEG_INF (-3.402823466e38f)   // jnp.finfo(float32).min == -FLT_MAX

// One block (256 thr = 4 waves) per query. C == 64 == wavefront size, so:
//   - each LANE owns one channel (acc = 1 VGPR),
//   - each WAVE owns all 64 channels and scans N/4 = 1024 points,
//   - hits are found per-lane, published via __ballot (wave-uniform SGPR),
//     then consumed by a UNIFORM scalar bit-loop: all 64 lanes cooperatively
//     load the hit row values[p][0..63] (one coalesced 256 B transaction)
//     and fmax into acc. ~41 expected hits/query spread over 4 waves.
// No LDS list, no atomics, no divergent branches, ONE barrier.
// LDS = 1 KB, VGPRs tiny -> 8 blocks/CU resident (32 waves/CU).
__global__ __launch_bounds__(256) void maxpool_box_kernel(
    const float* __restrict__ values,    // [N, C]
    const float* __restrict__ coords,    // [N, 2]
    const float* __restrict__ qcoords,   // [M, 2]
    float* __restrict__ out)             // [M, C]
{
    __shared__ float s_acc[4][64];       // per-wave partials, 1 KB

    const int q    = blockIdx.x;
    const int tid  = threadIdx.x;        // 0..255
    const int lane = tid & 63;           // == channel for the accumulator
    const int w    = tid >> 6;           // wave id 0..3

    const float qx = qcoords[2 * q + 0];
    const float qy = qcoords[2 * q + 1];

    const float4* c4p = (const float4*)coords;   // one float4 = coords of 2 points
    float acc = NEG_INF;

    // Wave w scans points [w*1024, (w+1)*1024): 8 iters x 64 lanes x 2 points.
    #pragma unroll
    for (int it = 0; it < 8; ++it) {
        const int pairbase = (w << 9) + (it << 6);     // w*512 + it*64
        const float4 cc = c4p[pairbase + lane];        // coalesced 16 B/lane
        // Bit-identical to reference: strict '<' on f32 |q - c|.
        const bool in0 = (fabsf(qx - cc.x) < HALF_KW) && (fabsf(qy - cc.y) < HALF_KW);
        const bool in1 = (fabsf(qx - cc.z) < HALF_KW) && (fabsf(qy - cc.w) < HALF_KW);
        unsigned long long b0 = __ballot(in0);
        unsigned long long b1 = __ballot(in1);
        // Uniform scalar bit-loops: no lane divergence; each hit row is one
        // coalesced 64-lane x 4 B load (lane == channel).
        while (b0) {
            const int i = __builtin_ctzll(b0); b0 &= b0 - 1;
            const int p = 2 * (pairbase + i);          // even point of the pair
            acc = fmaxf(acc, values[p * C + lane]);
        }
        while (b1) {
            const int i = __builtin_ctzll(b1); b1 &= b1 - 1;
            const int p = 2 * (pairbase + i) + 1;      // odd point of the pair
            acc = fmaxf(acc, values[p * C + lane]);
        }
    }

    // Cross-wave reduce: 4 partials per channel. (cnt==0 -> NEG_INF, matches
    // reference's jnp.finfo(f32).min fill.)
    s_acc[w][lane] = acc;                // banks: 2 lanes/bank, conflict-free
    __syncthreads();
    if (tid < 64) {
        const float r = fmaxf(fmaxf(s_acc[0][tid], s_acc[1][tid]),
                              fmaxf(s_acc[2][tid], s_acc[3][tid]));
        out[q * C + tid] = r;            // coalesced 256 B row store
    }
}

extern "C" void kernel_launch(void* const* d_in, const int* in_sizes, int n_in,
                              void* d_out, int out_size, void* d_ws, size_t ws_size,
                              hipStream_t stream) {
    const float* values  = (const float*)d_in[0];  // [4096, 64]
    const float* coords  = (const float*)d_in[1];  // [4096, 2]
    const float* qcoords = (const float*)d_in[2];  // [1024, 2]
    float* out = (float*)d_out;                    // [1024, 64]

    maxpool_box_kernel<<<M, 256, 0, stream>>>(values, coords, qcoords, out);
}

// Round 3
// 61.448 us; speedup vs baseline: 1.1001x; 1.0252x over previous
//
#include <hip/hip_runtime.h>

// Problem constants (match reference.py)
constexpr int N = 4096;   // points
constexpr int M = 1024;   // queries
constexpr int C = 64;     // channels (== wave width)
#define HALF_KW 0.05f     // kernel_size/2, strict '<' per reference
#define NEG_INF (-3.402823466e38f)   // jnp.finfo(float32).min == -FLT_MAX

// One block (256 thr = 4 waves) per query.
// Scan:   wave w tests points [w*1024,(w+1)*1024) via float4 coord loads
//         (2 points/lane/iter, 8 unrolled iters, all loads independent).
// Compact: per-wave ballot + mbcnt prefix -> each wave writes its hits into
//         its PRIVATE LDS segment. No atomics, no cross-wave coordination,
//         so NO barrier between scan and gather (same-wave LDS RAW only;
//         compiler inserts the lgkmcnt wait).
// Gather: round-0's verified high-MLP layout: lane=(sub<<4)|cq, each wave
//         loads 4 hit rows per iteration as float4 (1 KB/instruction).
//         Tail clamped to list[0] (duplicate harmless under max).
// Reduce: 16 partials per channel-quad; single barrier; 16 threads write out.
// No-hit case: acc stays NEG_INF == reference's finfo(f32).min fill.
__global__ __launch_bounds__(256) void maxpool_box_kernel(
    const float* __restrict__ values,    // [N, C]
    const float* __restrict__ coords,    // [N, 2]
    const float* __restrict__ qcoords,   // [M, 2]
    float* __restrict__ out)             // [M, C]
{
    __shared__ int    s_list[4][1024];   // per-wave hit lists (worst case), 16 KB
    __shared__ float4 s_part[16][16];    // [w*4+sub][cq], 4 KB

    const int q    = blockIdx.x;
    const int tid  = threadIdx.x;        // 0..255
    const int lane = tid & 63;
    const int w    = tid >> 6;           // wave id 0..3

    const float2 qc = ((const float2*)qcoords)[q];
    const float qx = qc.x, qy = qc.y;

    // ---- Scan + per-wave ballot compaction (no atomics, no barrier) ----
    const float4* c4p = (const float4*)coords;   // one float4 = coords of 2 points
    int cnt = 0;                                 // wave-uniform running count
    #pragma unroll
    for (int it = 0; it < 8; ++it) {
        const int pairbase = (w << 9) + (it << 6);     // w*512 + it*64
        const float4 cc = c4p[pairbase + lane];        // coalesced 16 B/lane
        // Bit-identical to reference: strict '<' on f32 |q - c|.
        const bool in0 = (fabsf(qx - cc.x) < HALF_KW) && (fabsf(qy - cc.y) < HALF_KW);
        const bool in1 = (fabsf(qx - cc.z) < HALF_KW) && (fabsf(qy - cc.w) < HALF_KW);
        const unsigned long long b0 = __ballot(in0);
        const unsigned long long b1 = __ballot(in1);
        // prefix popcount of mask below this lane (64-bit mbcnt idiom)
        int pos0 = __builtin_amdgcn_mbcnt_lo((unsigned)b0, 0);
        pos0     = __builtin_amdgcn_mbcnt_hi((unsigned)(b0 >> 32), pos0);
        if (in0) s_list[w][cnt + pos0] = 2 * (pairbase + lane);
        cnt += __popcll(b0);
        int pos1 = __builtin_amdgcn_mbcnt_lo((unsigned)b1, 0);
        pos1     = __builtin_amdgcn_mbcnt_hi((unsigned)(b1 >> 32), pos1);
        if (in1) s_list[w][cnt + pos1] = 2 * (pairbase + lane) + 1;
        cnt += __popcll(b1);
    }

    // ---- Grouped float4 gather of this wave's own list (high MLP) ----
    const int sub = lane >> 4;                   // point-in-group 0..3
    const int cq  = lane & 15;                   // channel quad 0..15
    const float4* v4 = (const float4*)values;    // [N][16] float4
    float4 acc = make_float4(NEG_INF, NEG_INF, NEG_INF, NEG_INF);
    const int G = (cnt + 3) >> 2;                // groups of 4 rows
    for (int g = 0; g < G; ++g) {
        const int t = (g << 2) + sub;
        const int p = s_list[w][t < cnt ? t : 0];  // clamp tail; dup harmless
        const float4 v = v4[p * 16 + cq];          // 4 rows x 256 B per wave inst
        acc.x = fmaxf(acc.x, v.x);
        acc.y = fmaxf(acc.y, v.y);
        acc.z = fmaxf(acc.z, v.z);
        acc.w = fmaxf(acc.w, v.w);
    }
    s_part[(w << 2) + sub][cq] = acc;
    __syncthreads();                             // the ONLY barrier

    // ---- Reduce 16 partials per channel quad, write out ----
    if (tid < 16) {
        float4 r = s_part[0][tid];
        #pragma unroll
        for (int k = 1; k < 16; ++k) {
            const float4 t = s_part[k][tid];
            r.x = fmaxf(r.x, t.x);
            r.y = fmaxf(r.y, t.y);
            r.z = fmaxf(r.z, t.z);
            r.w = fmaxf(r.w, t.w);
        }
        ((float4*)out)[q * 16 + tid] = r;        // coalesced 256 B row store
    }
}

extern "C" void kernel_launch(void* const* d_in, const int* in_sizes, int n_in,
                              void* d_out, int out_size, void* d_ws, size_t ws_size,
                              hipStream_t stream) {
    const float* values  = (const float*)d_in[0];  // [4096, 64]
    const float* coords  = (const float*)d_in[1];  // [4096, 2]
    const float* qcoords = (const float*)d_in[2];  // [1024, 2]
    float* out = (float*)d_out;                    // [1024, 64]

    maxpool_box_kernel<<<M, 256, 0, stream>>>(values, coords, qcoords, out);
}